// Round 9
// baseline (653.157 us; speedup 1.0000x reference)
//
#include <hip/hip_runtime.h>

#define DEVFN __device__ __forceinline__

constexpr int N    = 100000;
constexpr int F_IN = 166;
constexpr int HID  = 128;
constexpr int E    = 1600000;
constexpr int TOT  = E + N;          // edges + self-loops

// ---- workspace layout (bytes, all 16B-aligned) ----
constexpr size_t HW_OFF   = 0;            // hW [N,128] f32      51.2 MB
constexpr size_t ASRC_OFF = 51200000;     // a_src [N,4] f32      1.6 MB
constexpr size_t ADST_OFF = 52800000;     // a_dst [N,4] f32      1.6 MB
constexpr size_t DEG_OFF  = 54400000;     // deg [N] i32        400 KB (zeroed)
constexpr size_t ROW_OFF  = 54800000;     // rowstart [N+1] i32
constexpr size_t CUR_OFF  = 55300000;     // cursor [N] i32
constexpr size_t BSUM_OFF = 55700000;     // block sums [128] i32
constexpr size_t CSR_OFF  = 55710000;     // csr_src [TOT] i32   27.2 MB
constexpr size_t GOUT_OFF = 82910016;     // gat out [N,128] f32 51.2 MB

constexpr int SCAN_ELEMS = 1024;
constexpr int SCAN_NB    = (N + SCAN_ELEMS - 1) / SCAN_ELEMS;  // 98

constexpr int PROJ_ROWS  = 64;
constexpr int PROJ_NB    = (N + PROJ_ROWS - 1) / PROJ_ROWS;    // 1563

// xs stride: 172, not 168. The 4 wave-distinct row addresses are 4 rows
// apart; 4*172 dwords = 688 = 21*32 + 16 -> banks alternate {+0,+16} =
// 2-way aliasing (free). At 168: 4*168 = 672 = 21*32 -> 4-way same-bank
// conflict (R8: 494K conflicts, 1.22x regression). 172 = 0 mod 4 keeps
// 16B alignment for ds_read_b128.
constexpr int XS_STRIDE = 172;

DEVFN float lrelu(float e) { return e > 0.0f ? e : 0.2f * e; }

// ---------------------------------------------------------------------------
// K1: h = relu(x@W_in+b_in), hW = h@W_gat, a_src/a_dst = per-head hW·att
// Tile 64 rows x 128 cols, 256 threads, 4 rows x 8 cols per thread.
// W from global (VMEM/L1 pipe; R5 lesson), x/h from LDS broadcast reads.
// Each 16 B ds_read_b128 feeds 8 FMAs (R8 idea) with conflict-free padding
// (R9 fix). hs reuses the xs buffer (stride 132; 528 % 32 = 16 -> free).
// Tail: fused dst-degree histogram.
// ---------------------------------------------------------------------------
__global__ __launch_bounds__(256) void k_proj(
    const float* __restrict__ x, const float* __restrict__ Win,
    const float* __restrict__ bin, const float* __restrict__ Wgat,
    const float* __restrict__ attS, const float* __restrict__ attD,
    float* __restrict__ hW, float* __restrict__ aS, float* __restrict__ aD,
    const int* __restrict__ ei, int* __restrict__ deg)
{
    __shared__ __align__(16) float xs[PROJ_ROWS * XS_STRIDE];  // 44 KB; hs reuses
    float* hs = xs;

    const int t = threadIdx.x;
    const int row0 = blockIdx.x * PROJ_ROWS;
    const int cgrp = t & 15, rgrp = t >> 4;
    const int c0 = cgrp * 8;          // 8 cols
    const int r0 = rgrp * 4;          // 4 rows

    // ---- stage x tile (row-major, stride XS_STRIDE), float2 granules ----
    for (int idx = t; idx < PROJ_ROWS * 83; idx += 256) {
        const int r = idx / 83, kk = idx - r * 83;
        float2 v = make_float2(0.f, 0.f);
        if (row0 + r < N)
            v = *(const float2*)&x[(size_t)(row0 + r) * F_IN + 2 * kk];
        *(float2*)&xs[r * XS_STRIDE + 2 * kk] = v;
    }
    __syncthreads();

    float acc[4][8];
#pragma unroll
    for (int r = 0; r < 4; ++r)
#pragma unroll
        for (int c = 0; c < 8; ++c) acc[r][c] = 0.0f;

#define FMA8(R, XC, WA, WB)                                                    \
    acc[R][0] = fmaf(XC, WA.x, acc[R][0]);                                     \
    acc[R][1] = fmaf(XC, WA.y, acc[R][1]);                                     \
    acc[R][2] = fmaf(XC, WA.z, acc[R][2]);                                     \
    acc[R][3] = fmaf(XC, WA.w, acc[R][3]);                                     \
    acc[R][4] = fmaf(XC, WB.x, acc[R][4]);                                     \
    acc[R][5] = fmaf(XC, WB.y, acc[R][5]);                                     \
    acc[R][6] = fmaf(XC, WB.z, acc[R][6]);                                     \
    acc[R][7] = fmaf(XC, WB.w, acc[R][7]);

    // ---- GEMM1: h = relu(x@Win + bin), K = 166 = 41*4 + 2 ----
    for (int k = 0; k < 164; k += 4) {
        const float4 wa0 = *(const float4*)&Win[(size_t)(k + 0) * HID + c0];
        const float4 wb0 = *(const float4*)&Win[(size_t)(k + 0) * HID + c0 + 4];
        const float4 wa1 = *(const float4*)&Win[(size_t)(k + 1) * HID + c0];
        const float4 wb1 = *(const float4*)&Win[(size_t)(k + 1) * HID + c0 + 4];
        const float4 wa2 = *(const float4*)&Win[(size_t)(k + 2) * HID + c0];
        const float4 wb2 = *(const float4*)&Win[(size_t)(k + 2) * HID + c0 + 4];
        const float4 wa3 = *(const float4*)&Win[(size_t)(k + 3) * HID + c0];
        const float4 wb3 = *(const float4*)&Win[(size_t)(k + 3) * HID + c0 + 4];
#pragma unroll
        for (int r = 0; r < 4; ++r) {
            const float4 xv = *(const float4*)&xs[(r0 + r) * XS_STRIDE + k];
            FMA8(r, xv.x, wa0, wb0)
            FMA8(r, xv.y, wa1, wb1)
            FMA8(r, xv.z, wa2, wb2)
            FMA8(r, xv.w, wa3, wb3)
        }
    }
    {   // k = 164,165 tail
        const float4 ta0 = *(const float4*)&Win[(size_t)164 * HID + c0];
        const float4 tb0 = *(const float4*)&Win[(size_t)164 * HID + c0 + 4];
        const float4 ta1 = *(const float4*)&Win[(size_t)165 * HID + c0];
        const float4 tb1 = *(const float4*)&Win[(size_t)165 * HID + c0 + 4];
#pragma unroll
        for (int r = 0; r < 4; ++r) {
            const float2 xv = *(const float2*)&xs[(r0 + r) * XS_STRIDE + 164];
            FMA8(r, xv.x, ta0, tb0)
            FMA8(r, xv.y, ta1, tb1)
        }
    }

    const float4 bba = *(const float4*)&bin[c0];
    const float4 bbb = *(const float4*)&bin[c0 + 4];
    __syncthreads();   // all waves done reading xs; safe to overwrite with hs

#pragma unroll
    for (int r = 0; r < 4; ++r) {
        float4 h0, h1;
        h0.x = fmaxf(acc[r][0] + bba.x, 0.0f);
        h0.y = fmaxf(acc[r][1] + bba.y, 0.0f);
        h0.z = fmaxf(acc[r][2] + bba.z, 0.0f);
        h0.w = fmaxf(acc[r][3] + bba.w, 0.0f);
        h1.x = fmaxf(acc[r][4] + bbb.x, 0.0f);
        h1.y = fmaxf(acc[r][5] + bbb.y, 0.0f);
        h1.z = fmaxf(acc[r][6] + bbb.z, 0.0f);
        h1.w = fmaxf(acc[r][7] + bbb.w, 0.0f);
        *(float4*)&hs[(r0 + r) * 132 + c0]     = h0;
        *(float4*)&hs[(r0 + r) * 132 + c0 + 4] = h1;
    }
    __syncthreads();

    // ---- GEMM2: hW = h@Wgat (K = 128) ----
#pragma unroll
    for (int r = 0; r < 4; ++r)
#pragma unroll
        for (int c = 0; c < 8; ++c) acc[r][c] = 0.0f;

    for (int k = 0; k < HID; k += 4) {
        const float4 wa0 = *(const float4*)&Wgat[(size_t)(k + 0) * HID + c0];
        const float4 wb0 = *(const float4*)&Wgat[(size_t)(k + 0) * HID + c0 + 4];
        const float4 wa1 = *(const float4*)&Wgat[(size_t)(k + 1) * HID + c0];
        const float4 wb1 = *(const float4*)&Wgat[(size_t)(k + 1) * HID + c0 + 4];
        const float4 wa2 = *(const float4*)&Wgat[(size_t)(k + 2) * HID + c0];
        const float4 wb2 = *(const float4*)&Wgat[(size_t)(k + 2) * HID + c0 + 4];
        const float4 wa3 = *(const float4*)&Wgat[(size_t)(k + 3) * HID + c0];
        const float4 wb3 = *(const float4*)&Wgat[(size_t)(k + 3) * HID + c0 + 4];
#pragma unroll
        for (int r = 0; r < 4; ++r) {
            const float4 hv = *(const float4*)&hs[(r0 + r) * 132 + k];
            FMA8(r, hv.x, wa0, wb0)
            FMA8(r, hv.y, wa1, wb1)
            FMA8(r, hv.z, wa2, wb2)
            FMA8(r, hv.w, wa3, wb3)
        }
    }
#undef FMA8

    // ---- epilogue: store hW rows; per-head att dots ----
    const float4 aSa = *(const float4*)&attS[c0];
    const float4 aSb = *(const float4*)&attS[c0 + 4];
    const float4 aDa = *(const float4*)&attD[c0];
    const float4 aDb = *(const float4*)&attD[c0 + 4];
    const int head = cgrp >> 2;   // c0/32

#pragma unroll
    for (int r = 0; r < 4; ++r) {
        const int row = row0 + r0 + r;
        float4 v0, v1;
        v0.x = acc[r][0]; v0.y = acc[r][1]; v0.z = acc[r][2]; v0.w = acc[r][3];
        v1.x = acc[r][4]; v1.y = acc[r][5]; v1.z = acc[r][6]; v1.w = acc[r][7];
        if (row < N) {
            *(float4*)&hW[(size_t)row * HID + c0]     = v0;
            *(float4*)&hW[(size_t)row * HID + c0 + 4] = v1;
        }
        float ps = v0.x * aSa.x + v0.y * aSa.y + v0.z * aSa.z + v0.w * aSa.w
                 + v1.x * aSb.x + v1.y * aSb.y + v1.z * aSb.z + v1.w * aSb.w;
        float pd = v0.x * aDa.x + v0.y * aDa.y + v0.z * aDa.z + v0.w * aDa.w
                 + v1.x * aDb.x + v1.y * aDb.y + v1.z * aDb.z + v1.w * aDb.w;
        ps += __shfl_xor(ps, 1); ps += __shfl_xor(ps, 2);
        pd += __shfl_xor(pd, 1); pd += __shfl_xor(pd, 2);
        if ((cgrp & 3) == 0 && row < N) {
            aS[row * 4 + head] = ps;
            aD[row * 4 + head] = pd;
        }
    }

    // ---- fused dst-degree histogram (k_hist) ----
    const int stride = gridDim.x * 256;
    for (int i = blockIdx.x * 256 + t; i < TOT; i += stride) {
        const int d = (i < E) ? ei[E + i] : (i - E);
        atomicAdd(&deg[d], 1);
    }
}

// ---------------------------------------------------------------------------
// CSR build: scan1 (block sums) -> scan23 (inline bsum prefix + per-elem scan)
// ---------------------------------------------------------------------------
__global__ __launch_bounds__(256) void k_scan1(const int* __restrict__ deg,
                                               int* __restrict__ bsum)
{
    __shared__ int sd[256];
    const int t = threadIdx.x, b = blockIdx.x;
    int s = 0;
    int i0 = b * SCAN_ELEMS + t * 4;
#pragma unroll
    for (int k = 0; k < 4; ++k) {
        int i = i0 + k;
        s += (i < N) ? deg[i] : 0;
    }
    sd[t] = s;
    __syncthreads();
    for (int off = 128; off >= 1; off >>= 1) {
        if (t < off) sd[t] += sd[t + off];
        __syncthreads();
    }
    if (t == 0) bsum[b] = sd[0];
}

__global__ __launch_bounds__(256) void k_scan23(const int* __restrict__ deg,
                                                const int* __restrict__ bsum,
                                                int* __restrict__ rowstart,
                                                int* __restrict__ cursor)
{
    __shared__ int sd[256];
    __shared__ int boff_s;
    const int t = threadIdx.x, b = blockIdx.x;

    sd[t] = (t < b) ? bsum[t] : 0;
    __syncthreads();
    for (int off = 128; off >= 1; off >>= 1) {
        if (t < off) sd[t] += sd[t + off];
        __syncthreads();
    }
    if (t == 0) boff_s = sd[0];
    __syncthreads();
    const int base0 = boff_s;
    __syncthreads();

    const int i0 = b * SCAN_ELEMS + t * 4;
    int d0 = (i0 + 0 < N) ? deg[i0 + 0] : 0;
    int d1 = (i0 + 1 < N) ? deg[i0 + 1] : 0;
    int d2 = (i0 + 2 < N) ? deg[i0 + 2] : 0;
    int d3 = (i0 + 3 < N) ? deg[i0 + 3] : 0;
    int tsum = d0 + d1 + d2 + d3;
    sd[t] = tsum;
    __syncthreads();
    for (int off = 1; off < 256; off <<= 1) {
        int v = (t >= off) ? sd[t - off] : 0;
        __syncthreads();
        sd[t] += v;
        __syncthreads();
    }
    int base = base0 + sd[t] - tsum;
    int e0 = base, e1 = base + d0, e2 = e1 + d1, e3 = e2 + d2;
    if (i0 + 0 < N) { rowstart[i0 + 0] = e0; cursor[i0 + 0] = e0; }
    if (i0 + 1 < N) { rowstart[i0 + 1] = e1; cursor[i0 + 1] = e1; }
    if (i0 + 2 < N) { rowstart[i0 + 2] = e2; cursor[i0 + 2] = e2; }
    if (i0 + 3 < N) { rowstart[i0 + 3] = e3; cursor[i0 + 3] = e3; }
    if (b == 0 && t == 0) rowstart[N] = TOT;
}

__global__ __launch_bounds__(256) void k_scatter(const int* __restrict__ ei,
                                                 int* __restrict__ cursor,
                                                 int* __restrict__ csr)
{
    int i = blockIdx.x * 256 + threadIdx.x;
    if (i >= TOT) return;
    int s, d;
    if (i < E) { s = ei[i]; d = ei[E + i]; } else { s = i - E; d = s; }
    int pos = atomicAdd(&cursor[d], 1);
    csr[pos] = s;
}

// ---------------------------------------------------------------------------
// K_agg: one wave per dst node; lane = slot(4) x colgroup(16); 4 edges in
// flight x unroll 2 = 8 outstanding hW-row gathers. No max pass (|e| < 1,
// exp cannot overflow; softmax is shift-invariant). No LDS -> full occupancy.
// ---------------------------------------------------------------------------
__global__ __launch_bounds__(256) void k_agg(
    const int* __restrict__ rowstart, const int* __restrict__ csr,
    const float* __restrict__ aS, const float* __restrict__ aD,
    const float4* __restrict__ hW4, const float4* __restrict__ bgat4,
    float4* __restrict__ gout4)
{
    const int t = threadIdx.x;
    const int n = blockIdx.x * 4 + (t >> 6);
    const int lane = t & 63;
    const int slot = lane >> 4;      // which of 4 parallel edges
    const int cg   = lane & 15;      // colgroup: cols [cg*8, cg*8+8)
    const int head = cg >> 2;

    const int r0 = rowstart[n], r1 = rowstart[n + 1];
    const float adh = aD[n * 4 + head];

    float4 acc0 = {0.f, 0.f, 0.f, 0.f};
    float4 acc1 = {0.f, 0.f, 0.f, 0.f};
    float ss = 0.0f;

    int j = r0 + slot;
    for (; j + 4 < r1; j += 8) {
        const int s0 = csr[j], s1 = csr[j + 4];
        const float x0 = __expf(lrelu(aS[s0 * 4 + head] + adh));
        const float x1 = __expf(lrelu(aS[s1 * 4 + head] + adh));
        const float4 ha0 = hW4[(size_t)s0 * 32 + cg * 2 + 0];
        const float4 hb0 = hW4[(size_t)s0 * 32 + cg * 2 + 1];
        const float4 ha1 = hW4[(size_t)s1 * 32 + cg * 2 + 0];
        const float4 hb1 = hW4[(size_t)s1 * 32 + cg * 2 + 1];
        acc0.x = fmaf(ha0.x, x0, acc0.x); acc0.y = fmaf(ha0.y, x0, acc0.y);
        acc0.z = fmaf(ha0.z, x0, acc0.z); acc0.w = fmaf(ha0.w, x0, acc0.w);
        acc1.x = fmaf(hb0.x, x0, acc1.x); acc1.y = fmaf(hb0.y, x0, acc1.y);
        acc1.z = fmaf(hb0.z, x0, acc1.z); acc1.w = fmaf(hb0.w, x0, acc1.w);
        acc0.x = fmaf(ha1.x, x1, acc0.x); acc0.y = fmaf(ha1.y, x1, acc0.y);
        acc0.z = fmaf(ha1.z, x1, acc0.z); acc0.w = fmaf(ha1.w, x1, acc0.w);
        acc1.x = fmaf(hb1.x, x1, acc1.x); acc1.y = fmaf(hb1.y, x1, acc1.y);
        acc1.z = fmaf(hb1.z, x1, acc1.z); acc1.w = fmaf(hb1.w, x1, acc1.w);
        ss += x0 + x1;
    }
    if (j < r1) {
        const int s0 = csr[j];
        const float x0 = __expf(lrelu(aS[s0 * 4 + head] + adh));
        const float4 ha0 = hW4[(size_t)s0 * 32 + cg * 2 + 0];
        const float4 hb0 = hW4[(size_t)s0 * 32 + cg * 2 + 1];
        acc0.x = fmaf(ha0.x, x0, acc0.x); acc0.y = fmaf(ha0.y, x0, acc0.y);
        acc0.z = fmaf(ha0.z, x0, acc0.z); acc0.w = fmaf(ha0.w, x0, acc0.w);
        acc1.x = fmaf(hb0.x, x0, acc1.x); acc1.y = fmaf(hb0.y, x0, acc1.y);
        acc1.z = fmaf(hb0.z, x0, acc1.z); acc1.w = fmaf(hb0.w, x0, acc1.w);
        ss += x0;
    }

#pragma unroll
    for (int off = 16; off <= 32; off <<= 1) {
        acc0.x += __shfl_xor(acc0.x, off); acc0.y += __shfl_xor(acc0.y, off);
        acc0.z += __shfl_xor(acc0.z, off); acc0.w += __shfl_xor(acc0.w, off);
        acc1.x += __shfl_xor(acc1.x, off); acc1.y += __shfl_xor(acc1.y, off);
        acc1.z += __shfl_xor(acc1.z, off); acc1.w += __shfl_xor(acc1.w, off);
        ss += __shfl_xor(ss, off);
    }

    if (slot == 0) {
        const float inv = 1.0f / (ss + 1e-16f);
        const float4 bg0 = bgat4[cg * 2 + 0];
        const float4 bg1 = bgat4[cg * 2 + 1];
        float4 o0, o1;
        o0.x = acc0.x * inv + bg0.x; o0.y = acc0.y * inv + bg0.y;
        o0.z = acc0.z * inv + bg0.z; o0.w = acc0.w * inv + bg0.w;
        o1.x = acc1.x * inv + bg1.x; o1.y = acc1.y * inv + bg1.y;
        o1.z = acc1.z * inv + bg1.z; o1.w = acc1.w * inv + bg1.w;
        gout4[(size_t)n * 32 + cg * 2 + 0] = o0;
        gout4[(size_t)n * 32 + cg * 2 + 1] = o1;
    }
}

// ---------------------------------------------------------------------------
// K_mlp: h2 = relu(gout@W1+b1); logits = h2@W2+b2. One wave per node,
// 16 nodes/block (4 waves x 4 iters), W1 staged in LDS.
// ---------------------------------------------------------------------------
__global__ __launch_bounds__(256) void k_mlp(
    const float* __restrict__ gout,
    const float* __restrict__ W1, const float* __restrict__ b1,
    const float* __restrict__ W2, const float* __restrict__ b2,
    float2* __restrict__ out)
{
    __shared__ __align__(16) float W1l[HID * 64];
    __shared__ __align__(16) float rowbuf[4][HID];
    __shared__ float b1l[64];
    __shared__ float W2l[128];
    __shared__ float b2l[2];

    const int t = threadIdx.x;
    for (int idx = t; idx < HID * 64; idx += 256) W1l[idx] = W1[idx];
    if (t < 64) b1l[t] = b1[t];
    if (t < 128) W2l[t] = W2[t];
    if (t < 2) b2l[t] = b2[t];
    __syncthreads();

    const int w = t >> 6, lane = t & 63;

    for (int it = 0; it < 4; ++it) {
        const int n = blockIdx.x * 16 + w * 4 + it;
        const float2 oa = *(const float2*)&gout[(size_t)n * HID + lane * 2];
        rowbuf[w][lane * 2 + 0] = oa.x;
        rowbuf[w][lane * 2 + 1] = oa.y;

        float acc = b1l[lane];
#pragma unroll 4
        for (int k = 0; k < HID; k += 4) {
            const float4 bv = *(const float4*)&rowbuf[w][k];
            acc = fmaf(bv.x, W1l[(k + 0) * 64 + lane], acc);
            acc = fmaf(bv.y, W1l[(k + 1) * 64 + lane], acc);
            acc = fmaf(bv.z, W1l[(k + 2) * 64 + lane], acc);
            acc = fmaf(bv.w, W1l[(k + 3) * 64 + lane], acc);
        }
        acc = acc > 0.0f ? acc : 0.0f;

        float l0 = acc * W2l[lane * 2 + 0];
        float l1 = acc * W2l[lane * 2 + 1];
#pragma unroll
        for (int off = 32; off >= 1; off >>= 1) {
            l0 += __shfl_xor(l0, off);
            l1 += __shfl_xor(l1, off);
        }
        if (lane == 0) out[n] = make_float2(l0 + b2l[0], l1 + b2l[1]);
    }
}

extern "C" void kernel_launch(void* const* d_in, const int* in_sizes, int n_in,
                              void* d_out, int out_size, void* d_ws, size_t ws_size,
                              hipStream_t stream) {
    const float* x     = (const float*)d_in[0];
    const int*   ei    = (const int*)d_in[1];
    const float* Win   = (const float*)d_in[2];
    const float* bin   = (const float*)d_in[3];
    const float* Wgat  = (const float*)d_in[4];
    const float* attS  = (const float*)d_in[5];
    const float* attD  = (const float*)d_in[6];
    const float* bgat  = (const float*)d_in[7];
    const float* W1    = (const float*)d_in[8];
    const float* b1    = (const float*)d_in[9];
    const float* W2    = (const float*)d_in[10];
    const float* b2    = (const float*)d_in[11];

    char* ws = (char*)d_ws;
    float* hW    = (float*)(ws + HW_OFF);
    float* aS    = (float*)(ws + ASRC_OFF);
    float* aD    = (float*)(ws + ADST_OFF);
    int*   deg   = (int*)(ws + DEG_OFF);
    int*   row   = (int*)(ws + ROW_OFF);
    int*   cur   = (int*)(ws + CUR_OFF);
    int*   bsum  = (int*)(ws + BSUM_OFF);
    int*   csr   = (int*)(ws + CSR_OFF);
    float* gout  = (float*)(ws + GOUT_OFF);

    hipMemsetAsync(ws + DEG_OFF, 0, N * sizeof(int), stream);

    k_proj<<<PROJ_NB, 256, 0, stream>>>(x, Win, bin, Wgat, attS, attD,
                                        hW, aS, aD, ei, deg);
    k_scan1<<<SCAN_NB, 256, 0, stream>>>(deg, bsum);
    k_scan23<<<SCAN_NB, 256, 0, stream>>>(deg, bsum, row, cur);
    k_scatter<<<(TOT + 255) / 256, 256, 0, stream>>>(ei, cur, csr);
    k_agg<<<N / 4, 256, 0, stream>>>(row, csr, aS, aD, (const float4*)hW,
                                     (const float4*)bgat, (float4*)gout);
    k_mlp<<<N / 16, 256, 0, stream>>>(gout, W1, b1, W2, b2, (float2*)d_out);
}

// Round 10
// 611.259 us; speedup vs baseline: 1.0685x; 1.0685x over previous
//
#include <hip/hip_runtime.h>

#define DEVFN __device__ __forceinline__

constexpr int N    = 100000;
constexpr int F_IN = 166;
constexpr int HID  = 128;
constexpr int E    = 1600000;
constexpr int TOT  = E + N;          // edges + self-loops

// ---- workspace layout (bytes, all 16B-aligned) ----
constexpr size_t HW_OFF   = 0;            // hW [N,128] f32      51.2 MB
constexpr size_t ASRC_OFF = 51200000;     // a_src [N,4] f32      1.6 MB
constexpr size_t ADST_OFF = 52800000;     // a_dst [N,4] f32      1.6 MB
constexpr size_t DEG_OFF  = 54400000;     // deg [N] i32        400 KB (zeroed)
constexpr size_t ROW_OFF  = 54800000;     // rowstart [N+1] i32
constexpr size_t CUR_OFF  = 55300000;     // cursor [N] i32
constexpr size_t BSUM_OFF = 55700000;     // block sums [128] i32
constexpr size_t CSR_OFF  = 55710000;     // csr_src [TOT] i32   27.2 MB
constexpr size_t GOUT_OFF = 82910016;     // gat out [N,128] f32 51.2 MB

constexpr int SCAN_ELEMS = 1024;
constexpr int SCAN_NB    = (N + SCAN_ELEMS - 1) / SCAN_ELEMS;  // 98

constexpr int PROJ_ROWS  = 64;
constexpr int PROJ_NB    = (N + PROJ_ROWS - 1) / PROJ_ROWS;    // 1563

DEVFN float lrelu(float e) { return e > 0.0f ? e : 0.2f * e; }

// ---------------------------------------------------------------------------
// K1 (R7 version — best measured: 178 us incl fused hist, 94K conflicts).
// Tile 64 rows x 128 cols, 256 threads, 8 rows x 4 cols per thread.
// W from global (VMEM/L1; R5 lesson: LDS-staging W regressed), x/h from LDS
// broadcast. W software-pipelined 1 iter ahead. R8/R9 lesson: 4x8 retile
// regressed (5.3x conflicts, source not xs-stride — do not revisit).
// Tail: fused dst-degree histogram.
// ---------------------------------------------------------------------------
__global__ __launch_bounds__(256) void k_proj(
    const float* __restrict__ x, const float* __restrict__ Win,
    const float* __restrict__ bin, const float* __restrict__ Wgat,
    const float* __restrict__ attS, const float* __restrict__ attD,
    float* __restrict__ hW, float* __restrict__ aS, float* __restrict__ aD,
    const int* __restrict__ ei, int* __restrict__ deg)
{
    __shared__ __align__(16) float xs[PROJ_ROWS * 168];   // 43 KB; hs reuses (stride 132)
    float* hs = xs;

    const int t = threadIdx.x;
    const int row0 = blockIdx.x * PROJ_ROWS;
    const int cgrp = t & 31, rgrp = t >> 5;
    const int c0 = cgrp * 4;          // 4 cols
    const int r0 = rgrp * 8;          // 8 rows

    // ---- stage x tile (row-major, stride 168), float2 granules ----
    for (int idx = t; idx < PROJ_ROWS * 83; idx += 256) {
        const int r = idx / 83, kk = idx - r * 83;
        float2 v = make_float2(0.f, 0.f);
        if (row0 + r < N)
            v = *(const float2*)&x[(size_t)(row0 + r) * F_IN + 2 * kk];
        *(float2*)&xs[r * 168 + 2 * kk] = v;
    }
    __syncthreads();

    float acc[8][4];
#pragma unroll
    for (int r = 0; r < 8; ++r)
#pragma unroll
        for (int c = 0; c < 4; ++c) acc[r][c] = 0.0f;

#define FMA_BLOCK(SRC, STRIDE, KOFF, W0, W1, W2, W3)                           \
    _Pragma("unroll")                                                          \
    for (int r = 0; r < 8; ++r) {                                              \
        const float4 xv = *(const float4*)&SRC[(r0 + r) * STRIDE + (KOFF)];    \
        acc[r][0] = fmaf(xv.x, W0.x, fmaf(xv.y, W1.x,                          \
                    fmaf(xv.z, W2.x, fmaf(xv.w, W3.x, acc[r][0]))));           \
        acc[r][1] = fmaf(xv.x, W0.y, fmaf(xv.y, W1.y,                          \
                    fmaf(xv.z, W2.y, fmaf(xv.w, W3.y, acc[r][1]))));           \
        acc[r][2] = fmaf(xv.x, W0.z, fmaf(xv.y, W1.z,                          \
                    fmaf(xv.z, W2.z, fmaf(xv.w, W3.z, acc[r][2]))));           \
        acc[r][3] = fmaf(xv.x, W0.w, fmaf(xv.y, W1.w,                          \
                    fmaf(xv.z, W2.w, fmaf(xv.w, W3.w, acc[r][3]))));           \
    }

    // ---- GEMM1: h = relu(x@Win + bin), W pipelined 1 iter ahead ----
    {
        float4 w0 = *(const float4*)&Win[(size_t)0 * HID + c0];
        float4 w1 = *(const float4*)&Win[(size_t)1 * HID + c0];
        float4 w2 = *(const float4*)&Win[(size_t)2 * HID + c0];
        float4 w3 = *(const float4*)&Win[(size_t)3 * HID + c0];
        for (int k = 0; k < 160; k += 4) {
            const float4 n0 = *(const float4*)&Win[(size_t)(k + 4) * HID + c0];
            const float4 n1 = *(const float4*)&Win[(size_t)(k + 5) * HID + c0];
            const float4 n2 = *(const float4*)&Win[(size_t)(k + 6) * HID + c0];
            const float4 n3 = *(const float4*)&Win[(size_t)(k + 7) * HID + c0];
            FMA_BLOCK(xs, 168, k, w0, w1, w2, w3)
            w0 = n0; w1 = n1; w2 = n2; w3 = n3;
        }
        FMA_BLOCK(xs, 168, 160, w0, w1, w2, w3)
        // k = 164,165 tail (F_IN = 166)
        const float4 t0 = *(const float4*)&Win[(size_t)164 * HID + c0];
        const float4 t1 = *(const float4*)&Win[(size_t)165 * HID + c0];
#pragma unroll
        for (int r = 0; r < 8; ++r) {
            const float2 xv = *(const float2*)&xs[(r0 + r) * 168 + 164];
            acc[r][0] = fmaf(xv.x, t0.x, fmaf(xv.y, t1.x, acc[r][0]));
            acc[r][1] = fmaf(xv.x, t0.y, fmaf(xv.y, t1.y, acc[r][1]));
            acc[r][2] = fmaf(xv.x, t0.z, fmaf(xv.y, t1.z, acc[r][2]));
            acc[r][3] = fmaf(xv.x, t0.w, fmaf(xv.y, t1.w, acc[r][3]));
        }
    }

    const float4 bb = *(const float4*)&bin[c0];
    __syncthreads();   // all waves done reading xs; safe to overwrite with hs

#pragma unroll
    for (int r = 0; r < 8; ++r) {
        float4 h;
        h.x = fmaxf(acc[r][0] + bb.x, 0.0f);
        h.y = fmaxf(acc[r][1] + bb.y, 0.0f);
        h.z = fmaxf(acc[r][2] + bb.z, 0.0f);
        h.w = fmaxf(acc[r][3] + bb.w, 0.0f);
        *(float4*)&hs[(r0 + r) * 132 + c0] = h;
    }
    __syncthreads();

    // ---- GEMM2: hW = h@Wgat (K = 128), W pipelined 1 iter ahead ----
#pragma unroll
    for (int r = 0; r < 8; ++r)
#pragma unroll
        for (int c = 0; c < 4; ++c) acc[r][c] = 0.0f;

    {
        float4 w0 = *(const float4*)&Wgat[(size_t)0 * HID + c0];
        float4 w1 = *(const float4*)&Wgat[(size_t)1 * HID + c0];
        float4 w2 = *(const float4*)&Wgat[(size_t)2 * HID + c0];
        float4 w3 = *(const float4*)&Wgat[(size_t)3 * HID + c0];
        for (int k = 0; k < 124; k += 4) {
            const float4 n0 = *(const float4*)&Wgat[(size_t)(k + 4) * HID + c0];
            const float4 n1 = *(const float4*)&Wgat[(size_t)(k + 5) * HID + c0];
            const float4 n2 = *(const float4*)&Wgat[(size_t)(k + 6) * HID + c0];
            const float4 n3 = *(const float4*)&Wgat[(size_t)(k + 7) * HID + c0];
            FMA_BLOCK(hs, 132, k, w0, w1, w2, w3)
            w0 = n0; w1 = n1; w2 = n2; w3 = n3;
        }
        FMA_BLOCK(hs, 132, 124, w0, w1, w2, w3)
    }
#undef FMA_BLOCK

    // ---- epilogue: store hW rows; per-head att dots ----
    const float4 atS = *(const float4*)&attS[c0];
    const float4 atD = *(const float4*)&attD[c0];
    const int head = cgrp >> 3;

#pragma unroll
    for (int r = 0; r < 8; ++r) {
        const int row = row0 + r0 + r;
        float4 v;
        v.x = acc[r][0]; v.y = acc[r][1]; v.z = acc[r][2]; v.w = acc[r][3];
        if (row < N)
            *(float4*)&hW[(size_t)row * HID + c0] = v;
        float ps = v.x * atS.x + v.y * atS.y + v.z * atS.z + v.w * atS.w;
        float pd = v.x * atD.x + v.y * atD.y + v.z * atD.z + v.w * atD.w;
#pragma unroll
        for (int off = 1; off <= 4; off <<= 1) {
            ps += __shfl_xor(ps, off);
            pd += __shfl_xor(pd, off);
        }
        if ((cgrp & 7) == 0 && row < N) {
            aS[row * 4 + head] = ps;
            aD[row * 4 + head] = pd;
        }
    }

    // ---- fused dst-degree histogram (k_hist) ----
    const int stride = gridDim.x * 256;
    for (int i = blockIdx.x * 256 + t; i < TOT; i += stride) {
        const int d = (i < E) ? ei[E + i] : (i - E);
        atomicAdd(&deg[d], 1);
    }
}

// ---------------------------------------------------------------------------
// CSR build: scan1 (block sums) -> scan23 (inline bsum prefix + per-elem scan)
// ---------------------------------------------------------------------------
__global__ __launch_bounds__(256) void k_scan1(const int* __restrict__ deg,
                                               int* __restrict__ bsum)
{
    __shared__ int sd[256];
    const int t = threadIdx.x, b = blockIdx.x;
    int s = 0;
    int i0 = b * SCAN_ELEMS + t * 4;
#pragma unroll
    for (int k = 0; k < 4; ++k) {
        int i = i0 + k;
        s += (i < N) ? deg[i] : 0;
    }
    sd[t] = s;
    __syncthreads();
    for (int off = 128; off >= 1; off >>= 1) {
        if (t < off) sd[t] += sd[t + off];
        __syncthreads();
    }
    if (t == 0) bsum[b] = sd[0];
}

__global__ __launch_bounds__(256) void k_scan23(const int* __restrict__ deg,
                                                const int* __restrict__ bsum,
                                                int* __restrict__ rowstart,
                                                int* __restrict__ cursor)
{
    __shared__ int sd[256];
    __shared__ int boff_s;
    const int t = threadIdx.x, b = blockIdx.x;

    sd[t] = (t < b) ? bsum[t] : 0;
    __syncthreads();
    for (int off = 128; off >= 1; off >>= 1) {
        if (t < off) sd[t] += sd[t + off];
        __syncthreads();
    }
    if (t == 0) boff_s = sd[0];
    __syncthreads();
    const int base0 = boff_s;
    __syncthreads();

    const int i0 = b * SCAN_ELEMS + t * 4;
    int d0 = (i0 + 0 < N) ? deg[i0 + 0] : 0;
    int d1 = (i0 + 1 < N) ? deg[i0 + 1] : 0;
    int d2 = (i0 + 2 < N) ? deg[i0 + 2] : 0;
    int d3 = (i0 + 3 < N) ? deg[i0 + 3] : 0;
    int tsum = d0 + d1 + d2 + d3;
    sd[t] = tsum;
    __syncthreads();
    for (int off = 1; off < 256; off <<= 1) {
        int v = (t >= off) ? sd[t - off] : 0;
        __syncthreads();
        sd[t] += v;
        __syncthreads();
    }
    int base = base0 + sd[t] - tsum;
    int e0 = base, e1 = base + d0, e2 = e1 + d1, e3 = e2 + d2;
    if (i0 + 0 < N) { rowstart[i0 + 0] = e0; cursor[i0 + 0] = e0; }
    if (i0 + 1 < N) { rowstart[i0 + 1] = e1; cursor[i0 + 1] = e1; }
    if (i0 + 2 < N) { rowstart[i0 + 2] = e2; cursor[i0 + 2] = e2; }
    if (i0 + 3 < N) { rowstart[i0 + 3] = e3; cursor[i0 + 3] = e3; }
    if (b == 0 && t == 0) rowstart[N] = TOT;
}

__global__ __launch_bounds__(256) void k_scatter(const int* __restrict__ ei,
                                                 int* __restrict__ cursor,
                                                 int* __restrict__ csr)
{
    int i = blockIdx.x * 256 + threadIdx.x;
    if (i >= TOT) return;
    int s, d;
    if (i < E) { s = ei[i]; d = ei[E + i]; } else { s = i - E; d = s; }
    int pos = atomicAdd(&cursor[d], 1);
    csr[pos] = s;
}

// ---------------------------------------------------------------------------
// K_agg (R10): one wave per dst node; lane = slot(8) x cg(8); 8 edges in
// parallel, each lane covers 16 cols (4 consecutive float4s = 64 B) -> with
// unroll 2, 8 hW float4 loads in flight per lane (2x R9) to hide the
// ~600-900 cyc L3 gather latency. No max pass (|e| < 1, exp can't overflow;
// softmax shift-invariant). No LDS -> full occupancy.
// ---------------------------------------------------------------------------
__global__ __launch_bounds__(256) void k_agg(
    const int* __restrict__ rowstart, const int* __restrict__ csr,
    const float* __restrict__ aS, const float* __restrict__ aD,
    const float4* __restrict__ hW4, const float4* __restrict__ bgat4,
    float4* __restrict__ gout4)
{
    const int t = threadIdx.x;
    const int n = blockIdx.x * 4 + (t >> 6);
    const int lane = t & 63;
    const int slot = lane >> 3;      // 8 parallel edge slots (lane bits 3..5)
    const int cg   = lane & 7;       // colgroup: cols [cg*16, cg*16+16)
    const int head = cg >> 1;

    const int r0 = rowstart[n], r1 = rowstart[n + 1];
    const float adh = aD[n * 4 + head];

    float4 a0 = {0.f,0.f,0.f,0.f}, a1 = {0.f,0.f,0.f,0.f};
    float4 a2 = {0.f,0.f,0.f,0.f}, a3 = {0.f,0.f,0.f,0.f};
    float ss = 0.0f;

#define ACC16(H0, H1, H2, H3, X)                                               \
    a0.x = fmaf(H0.x, X, a0.x); a0.y = fmaf(H0.y, X, a0.y);                    \
    a0.z = fmaf(H0.z, X, a0.z); a0.w = fmaf(H0.w, X, a0.w);                    \
    a1.x = fmaf(H1.x, X, a1.x); a1.y = fmaf(H1.y, X, a1.y);                    \
    a1.z = fmaf(H1.z, X, a1.z); a1.w = fmaf(H1.w, X, a1.w);                    \
    a2.x = fmaf(H2.x, X, a2.x); a2.y = fmaf(H2.y, X, a2.y);                    \
    a2.z = fmaf(H2.z, X, a2.z); a2.w = fmaf(H2.w, X, a2.w);                    \
    a3.x = fmaf(H3.x, X, a3.x); a3.y = fmaf(H3.y, X, a3.y);                    \
    a3.z = fmaf(H3.z, X, a3.z); a3.w = fmaf(H3.w, X, a3.w);

    int j = r0 + slot;
    for (; j + 8 < r1; j += 16) {
        const int s0 = csr[j], s1 = csr[j + 8];
        const float x0 = __expf(lrelu(aS[s0 * 4 + head] + adh));
        const float x1 = __expf(lrelu(aS[s1 * 4 + head] + adh));
        const float4* p0 = &hW4[(size_t)s0 * 32 + cg * 4];
        const float4* p1 = &hW4[(size_t)s1 * 32 + cg * 4];
        const float4 h00 = p0[0], h01 = p0[1], h02 = p0[2], h03 = p0[3];
        const float4 h10 = p1[0], h11 = p1[1], h12 = p1[2], h13 = p1[3];
        ACC16(h00, h01, h02, h03, x0)
        ACC16(h10, h11, h12, h13, x1)
        ss += x0 + x1;
    }
    if (j < r1) {
        const int s0 = csr[j];
        const float x0 = __expf(lrelu(aS[s0 * 4 + head] + adh));
        const float4* p0 = &hW4[(size_t)s0 * 32 + cg * 4];
        const float4 h00 = p0[0], h01 = p0[1], h02 = p0[2], h03 = p0[3];
        ACC16(h00, h01, h02, h03, x0)
        ss += x0;
    }
#undef ACC16

    // reduce across the 8 edge-slots (lane bits 3..5)
#pragma unroll
    for (int off = 8; off <= 32; off <<= 1) {
        a0.x += __shfl_xor(a0.x, off); a0.y += __shfl_xor(a0.y, off);
        a0.z += __shfl_xor(a0.z, off); a0.w += __shfl_xor(a0.w, off);
        a1.x += __shfl_xor(a1.x, off); a1.y += __shfl_xor(a1.y, off);
        a1.z += __shfl_xor(a1.z, off); a1.w += __shfl_xor(a1.w, off);
        a2.x += __shfl_xor(a2.x, off); a2.y += __shfl_xor(a2.y, off);
        a2.z += __shfl_xor(a2.z, off); a2.w += __shfl_xor(a2.w, off);
        a3.x += __shfl_xor(a3.x, off); a3.y += __shfl_xor(a3.y, off);
        a3.z += __shfl_xor(a3.z, off); a3.w += __shfl_xor(a3.w, off);
        ss += __shfl_xor(ss, off);
    }

    if (slot == 0) {
        const float inv = 1.0f / (ss + 1e-16f);
        const float4 bg0 = bgat4[cg * 4 + 0];
        const float4 bg1 = bgat4[cg * 4 + 1];
        const float4 bg2 = bgat4[cg * 4 + 2];
        const float4 bg3 = bgat4[cg * 4 + 3];
        float4 o0, o1, o2, o3;
        o0.x = a0.x * inv + bg0.x; o0.y = a0.y * inv + bg0.y;
        o0.z = a0.z * inv + bg0.z; o0.w = a0.w * inv + bg0.w;
        o1.x = a1.x * inv + bg1.x; o1.y = a1.y * inv + bg1.y;
        o1.z = a1.z * inv + bg1.z; o1.w = a1.w * inv + bg1.w;
        o2.x = a2.x * inv + bg2.x; o2.y = a2.y * inv + bg2.y;
        o2.z = a2.z * inv + bg2.z; o2.w = a2.w * inv + bg2.w;
        o3.x = a3.x * inv + bg3.x; o3.y = a3.y * inv + bg3.y;
        o3.z = a3.z * inv + bg3.z; o3.w = a3.w * inv + bg3.w;
        float4* po = &gout4[(size_t)n * 32 + cg * 4];
        po[0] = o0; po[1] = o1; po[2] = o2; po[3] = o3;
    }
}

// ---------------------------------------------------------------------------
// K_mlp: h2 = relu(gout@W1+b1); logits = h2@W2+b2. One wave per node,
// 16 nodes/block (4 waves x 4 iters), W1 staged in LDS.
// ---------------------------------------------------------------------------
__global__ __launch_bounds__(256) void k_mlp(
    const float* __restrict__ gout,
    const float* __restrict__ W1, const float* __restrict__ b1,
    const float* __restrict__ W2, const float* __restrict__ b2,
    float2* __restrict__ out)
{
    __shared__ __align__(16) float W1l[HID * 64];
    __shared__ __align__(16) float rowbuf[4][HID];
    __shared__ float b1l[64];
    __shared__ float W2l[128];
    __shared__ float b2l[2];

    const int t = threadIdx.x;
    for (int idx = t; idx < HID * 64; idx += 256) W1l[idx] = W1[idx];
    if (t < 64) b1l[t] = b1[t];
    if (t < 128) W2l[t] = W2[t];
    if (t < 2) b2l[t] = b2[t];
    __syncthreads();

    const int w = t >> 6, lane = t & 63;

    for (int it = 0; it < 4; ++it) {
        const int n = blockIdx.x * 16 + w * 4 + it;
        const float2 oa = *(const float2*)&gout[(size_t)n * HID + lane * 2];
        rowbuf[w][lane * 2 + 0] = oa.x;
        rowbuf[w][lane * 2 + 1] = oa.y;

        float acc = b1l[lane];
#pragma unroll 4
        for (int k = 0; k < HID; k += 4) {
            const float4 bv = *(const float4*)&rowbuf[w][k];
            acc = fmaf(bv.x, W1l[(k + 0) * 64 + lane], acc);
            acc = fmaf(bv.y, W1l[(k + 1) * 64 + lane], acc);
            acc = fmaf(bv.z, W1l[(k + 2) * 64 + lane], acc);
            acc = fmaf(bv.w, W1l[(k + 3) * 64 + lane], acc);
        }
        acc = acc > 0.0f ? acc : 0.0f;

        float l0 = acc * W2l[lane * 2 + 0];
        float l1 = acc * W2l[lane * 2 + 1];
#pragma unroll
        for (int off = 32; off >= 1; off >>= 1) {
            l0 += __shfl_xor(l0, off);
            l1 += __shfl_xor(l1, off);
        }
        if (lane == 0) out[n] = make_float2(l0 + b2l[0], l1 + b2l[1]);
    }
}

extern "C" void kernel_launch(void* const* d_in, const int* in_sizes, int n_in,
                              void* d_out, int out_size, void* d_ws, size_t ws_size,
                              hipStream_t stream) {
    const float* x     = (const float*)d_in[0];
    const int*   ei    = (const int*)d_in[1];
    const float* Win   = (const float*)d_in[2];
    const float* bin   = (const float*)d_in[3];
    const float* Wgat  = (const float*)d_in[4];
    const float* attS  = (const float*)d_in[5];
    const float* attD  = (const float*)d_in[6];
    const float* bgat  = (const float*)d_in[7];
    const float* W1    = (const float*)d_in[8];
    const float* b1    = (const float*)d_in[9];
    const float* W2    = (const float*)d_in[10];
    const float* b2    = (const float*)d_in[11];

    char* ws = (char*)d_ws;
    float* hW    = (float*)(ws + HW_OFF);
    float* aS    = (float*)(ws + ASRC_OFF);
    float* aD    = (float*)(ws + ADST_OFF);
    int*   deg   = (int*)(ws + DEG_OFF);
    int*   row   = (int*)(ws + ROW_OFF);
    int*   cur   = (int*)(ws + CUR_OFF);
    int*   bsum  = (int*)(ws + BSUM_OFF);
    int*   csr   = (int*)(ws + CSR_OFF);
    float* gout  = (float*)(ws + GOUT_OFF);

    hipMemsetAsync(ws + DEG_OFF, 0, N * sizeof(int), stream);

    k_proj<<<PROJ_NB, 256, 0, stream>>>(x, Win, bin, Wgat, attS, attD,
                                        hW, aS, aD, ei, deg);
    k_scan1<<<SCAN_NB, 256, 0, stream>>>(deg, bsum);
    k_scan23<<<SCAN_NB, 256, 0, stream>>>(deg, bsum, row, cur);
    k_scatter<<<(TOT + 255) / 256, 256, 0, stream>>>(ei, cur, csr);
    k_agg<<<N / 4, 256, 0, stream>>>(row, csr, aS, aD, (const float4*)hW,
                                     (const float4*)bgat, (float4*)gout);
    k_mlp<<<N / 16, 256, 0, stream>>>(gout, W1, b1, W2, b2, (float2*)d_out);
}

// Round 11
// 556.280 us; speedup vs baseline: 1.1742x; 1.0988x over previous
//
#include <hip/hip_runtime.h>

#define DEVFN __device__ __forceinline__

constexpr int N    = 100000;
constexpr int F_IN = 166;
constexpr int HID  = 128;
constexpr int E    = 1600000;

// ---- workspace layout (bytes, all 16B-aligned) ----
constexpr size_t HW_OFF   = 0;            // hW [N,128] f32      51.2 MB
constexpr size_t ASRC_OFF = 51200000;     // a_src [N,4] f32      1.6 MB
constexpr size_t ADST_OFF = 52800000;     // a_dst [N,4] f32      1.6 MB
constexpr size_t DEG_OFF  = 54400000;     // deg [N] i32        400 KB (zeroed)
constexpr size_t ROW_OFF  = 54800000;     // rowstart [N+1] i32
constexpr size_t CUR_OFF  = 55300000;     // cursor [N] i32
constexpr size_t BSUM_OFF = 55700000;     // block sums [128] i32
constexpr size_t CSR_OFF  = 55710000;     // csr_src [E] i32     25.6 MB (no self-loops)

constexpr int SCAN_ELEMS = 1024;
constexpr int SCAN_NB    = (N + SCAN_ELEMS - 1) / SCAN_ELEMS;  // 98

constexpr int PROJ_ROWS  = 64;
constexpr int PROJ_NB    = (N + PROJ_ROWS - 1) / PROJ_ROWS;    // 1563

DEVFN float lrelu(float e) { return e > 0.0f ? e : 0.2f * e; }

// ---------------------------------------------------------------------------
// K1 (R7/R10 version — best measured: ~180 us incl fused hist, 94K conflicts).
// Tile 64 rows x 128 cols, 256 threads, 8 rows x 4 cols per thread.
// W from global (R5 lesson: LDS-staging W regressed). R8/R9 lesson: 4x8
// retile regressed (5.3x conflicts) — do not revisit. Tail: fused
// dst-degree histogram over EDGES only (self-loops handled inline in k_agg).
// ---------------------------------------------------------------------------
__global__ __launch_bounds__(256) void k_proj(
    const float* __restrict__ x, const float* __restrict__ Win,
    const float* __restrict__ bin, const float* __restrict__ Wgat,
    const float* __restrict__ attS, const float* __restrict__ attD,
    float* __restrict__ hW, float* __restrict__ aS, float* __restrict__ aD,
    const int* __restrict__ ei, int* __restrict__ deg)
{
    __shared__ __align__(16) float xs[PROJ_ROWS * 168];   // 43 KB; hs reuses (stride 132)
    float* hs = xs;

    const int t = threadIdx.x;
    const int row0 = blockIdx.x * PROJ_ROWS;
    const int cgrp = t & 31, rgrp = t >> 5;
    const int c0 = cgrp * 4;          // 4 cols
    const int r0 = rgrp * 8;          // 8 rows

    for (int idx = t; idx < PROJ_ROWS * 83; idx += 256) {
        const int r = idx / 83, kk = idx - r * 83;
        float2 v = make_float2(0.f, 0.f);
        if (row0 + r < N)
            v = *(const float2*)&x[(size_t)(row0 + r) * F_IN + 2 * kk];
        *(float2*)&xs[r * 168 + 2 * kk] = v;
    }
    __syncthreads();

    float acc[8][4];
#pragma unroll
    for (int r = 0; r < 8; ++r)
#pragma unroll
        for (int c = 0; c < 4; ++c) acc[r][c] = 0.0f;

#define FMA_BLOCK(SRC, STRIDE, KOFF, W0, W1, W2, W3)                           \
    _Pragma("unroll")                                                          \
    for (int r = 0; r < 8; ++r) {                                              \
        const float4 xv = *(const float4*)&SRC[(r0 + r) * STRIDE + (KOFF)];    \
        acc[r][0] = fmaf(xv.x, W0.x, fmaf(xv.y, W1.x,                          \
                    fmaf(xv.z, W2.x, fmaf(xv.w, W3.x, acc[r][0]))));           \
        acc[r][1] = fmaf(xv.x, W0.y, fmaf(xv.y, W1.y,                          \
                    fmaf(xv.z, W2.y, fmaf(xv.w, W3.y, acc[r][1]))));           \
        acc[r][2] = fmaf(xv.x, W0.z, fmaf(xv.y, W1.z,                          \
                    fmaf(xv.z, W2.z, fmaf(xv.w, W3.z, acc[r][2]))));           \
        acc[r][3] = fmaf(xv.x, W0.w, fmaf(xv.y, W1.w,                          \
                    fmaf(xv.z, W2.w, fmaf(xv.w, W3.w, acc[r][3]))));           \
    }

    {   // GEMM1: h = relu(x@Win + bin), W pipelined 1 iter ahead
        float4 w0 = *(const float4*)&Win[(size_t)0 * HID + c0];
        float4 w1 = *(const float4*)&Win[(size_t)1 * HID + c0];
        float4 w2 = *(const float4*)&Win[(size_t)2 * HID + c0];
        float4 w3 = *(const float4*)&Win[(size_t)3 * HID + c0];
        for (int k = 0; k < 160; k += 4) {
            const float4 n0 = *(const float4*)&Win[(size_t)(k + 4) * HID + c0];
            const float4 n1 = *(const float4*)&Win[(size_t)(k + 5) * HID + c0];
            const float4 n2 = *(const float4*)&Win[(size_t)(k + 6) * HID + c0];
            const float4 n3 = *(const float4*)&Win[(size_t)(k + 7) * HID + c0];
            FMA_BLOCK(xs, 168, k, w0, w1, w2, w3)
            w0 = n0; w1 = n1; w2 = n2; w3 = n3;
        }
        FMA_BLOCK(xs, 168, 160, w0, w1, w2, w3)
        const float4 t0 = *(const float4*)&Win[(size_t)164 * HID + c0];
        const float4 t1 = *(const float4*)&Win[(size_t)165 * HID + c0];
#pragma unroll
        for (int r = 0; r < 8; ++r) {
            const float2 xv = *(const float2*)&xs[(r0 + r) * 168 + 164];
            acc[r][0] = fmaf(xv.x, t0.x, fmaf(xv.y, t1.x, acc[r][0]));
            acc[r][1] = fmaf(xv.x, t0.y, fmaf(xv.y, t1.y, acc[r][1]));
            acc[r][2] = fmaf(xv.x, t0.z, fmaf(xv.y, t1.z, acc[r][2]));
            acc[r][3] = fmaf(xv.x, t0.w, fmaf(xv.y, t1.w, acc[r][3]));
        }
    }

    const float4 bb = *(const float4*)&bin[c0];
    __syncthreads();

#pragma unroll
    for (int r = 0; r < 8; ++r) {
        float4 h;
        h.x = fmaxf(acc[r][0] + bb.x, 0.0f);
        h.y = fmaxf(acc[r][1] + bb.y, 0.0f);
        h.z = fmaxf(acc[r][2] + bb.z, 0.0f);
        h.w = fmaxf(acc[r][3] + bb.w, 0.0f);
        *(float4*)&hs[(r0 + r) * 132 + c0] = h;
    }
    __syncthreads();

#pragma unroll
    for (int r = 0; r < 8; ++r)
#pragma unroll
        for (int c = 0; c < 4; ++c) acc[r][c] = 0.0f;

    {   // GEMM2: hW = h@Wgat (K = 128), W pipelined 1 iter ahead
        float4 w0 = *(const float4*)&Wgat[(size_t)0 * HID + c0];
        float4 w1 = *(const float4*)&Wgat[(size_t)1 * HID + c0];
        float4 w2 = *(const float4*)&Wgat[(size_t)2 * HID + c0];
        float4 w3 = *(const float4*)&Wgat[(size_t)3 * HID + c0];
        for (int k = 0; k < 124; k += 4) {
            const float4 n0 = *(const float4*)&Wgat[(size_t)(k + 4) * HID + c0];
            const float4 n1 = *(const float4*)&Wgat[(size_t)(k + 5) * HID + c0];
            const float4 n2 = *(const float4*)&Wgat[(size_t)(k + 6) * HID + c0];
            const float4 n3 = *(const float4*)&Wgat[(size_t)(k + 7) * HID + c0];
            FMA_BLOCK(hs, 132, k, w0, w1, w2, w3)
            w0 = n0; w1 = n1; w2 = n2; w3 = n3;
        }
        FMA_BLOCK(hs, 132, 124, w0, w1, w2, w3)
    }
#undef FMA_BLOCK

    const float4 atS = *(const float4*)&attS[c0];
    const float4 atD = *(const float4*)&attD[c0];
    const int head = cgrp >> 3;

#pragma unroll
    for (int r = 0; r < 8; ++r) {
        const int row = row0 + r0 + r;
        float4 v;
        v.x = acc[r][0]; v.y = acc[r][1]; v.z = acc[r][2]; v.w = acc[r][3];
        if (row < N)
            *(float4*)&hW[(size_t)row * HID + c0] = v;
        float ps = v.x * atS.x + v.y * atS.y + v.z * atS.z + v.w * atS.w;
        float pd = v.x * atD.x + v.y * atD.y + v.z * atD.z + v.w * atD.w;
#pragma unroll
        for (int off = 1; off <= 4; off <<= 1) {
            ps += __shfl_xor(ps, off);
            pd += __shfl_xor(pd, off);
        }
        if ((cgrp & 7) == 0 && row < N) {
            aS[row * 4 + head] = ps;
            aD[row * 4 + head] = pd;
        }
    }

    // ---- fused dst-degree histogram over edges (self-loops excluded) ----
    const int stride = gridDim.x * 256;
    for (int i = blockIdx.x * 256 + t; i < E; i += stride) {
        atomicAdd(&deg[ei[E + i]], 1);
    }
}

// ---------------------------------------------------------------------------
// CSR build: scan1 (block sums) -> scan23 (inline bsum prefix + per-elem scan)
// ---------------------------------------------------------------------------
__global__ __launch_bounds__(256) void k_scan1(const int* __restrict__ deg,
                                               int* __restrict__ bsum)
{
    __shared__ int sd[256];
    const int t = threadIdx.x, b = blockIdx.x;
    int s = 0;
    int i0 = b * SCAN_ELEMS + t * 4;
#pragma unroll
    for (int k = 0; k < 4; ++k) {
        int i = i0 + k;
        s += (i < N) ? deg[i] : 0;
    }
    sd[t] = s;
    __syncthreads();
    for (int off = 128; off >= 1; off >>= 1) {
        if (t < off) sd[t] += sd[t + off];
        __syncthreads();
    }
    if (t == 0) bsum[b] = sd[0];
}

__global__ __launch_bounds__(256) void k_scan23(const int* __restrict__ deg,
                                                const int* __restrict__ bsum,
                                                int* __restrict__ rowstart,
                                                int* __restrict__ cursor)
{
    __shared__ int sd[256];
    __shared__ int boff_s;
    const int t = threadIdx.x, b = blockIdx.x;

    sd[t] = (t < b) ? bsum[t] : 0;
    __syncthreads();
    for (int off = 128; off >= 1; off >>= 1) {
        if (t < off) sd[t] += sd[t + off];
        __syncthreads();
    }
    if (t == 0) boff_s = sd[0];
    __syncthreads();
    const int base0 = boff_s;
    __syncthreads();

    const int i0 = b * SCAN_ELEMS + t * 4;
    int d0 = (i0 + 0 < N) ? deg[i0 + 0] : 0;
    int d1 = (i0 + 1 < N) ? deg[i0 + 1] : 0;
    int d2 = (i0 + 2 < N) ? deg[i0 + 2] : 0;
    int d3 = (i0 + 3 < N) ? deg[i0 + 3] : 0;
    int tsum = d0 + d1 + d2 + d3;
    sd[t] = tsum;
    __syncthreads();
    for (int off = 1; off < 256; off <<= 1) {
        int v = (t >= off) ? sd[t - off] : 0;
        __syncthreads();
        sd[t] += v;
        __syncthreads();
    }
    int base = base0 + sd[t] - tsum;
    int e0 = base, e1 = base + d0, e2 = e1 + d1, e3 = e2 + d2;
    if (i0 + 0 < N) { rowstart[i0 + 0] = e0; cursor[i0 + 0] = e0; }
    if (i0 + 1 < N) { rowstart[i0 + 1] = e1; cursor[i0 + 1] = e1; }
    if (i0 + 2 < N) { rowstart[i0 + 2] = e2; cursor[i0 + 2] = e2; }
    if (i0 + 3 < N) { rowstart[i0 + 3] = e3; cursor[i0 + 3] = e3; }
    if (b == 0 && t == 0) rowstart[N] = E;
}

__global__ __launch_bounds__(256) void k_scatter(const int* __restrict__ ei,
                                                 int* __restrict__ cursor,
                                                 int* __restrict__ csr)
{
    int i = blockIdx.x * 256 + threadIdx.x;
    if (i >= E) return;
    int s = ei[i], d = ei[E + i];
    int pos = atomicAdd(&cursor[d], 1);
    csr[pos] = s;
}

// ---------------------------------------------------------------------------
// K_agg (R11): one wave per dst node; lane = slot(8) x cg(8); aggregation +
// FUSED MLP head (no gout round-trip, no k_mlp kernel). Self-loop handled
// inline by slot-0 lanes (near-coalesced hW[n] read, not in CSR).
// MLP: 512 B/wave LDS rowbuf (2 KB/block — occupancy preserved, unlike a
// 32 KB W1 stage); W1 streamed from global = L1-resident after first node.
// ---------------------------------------------------------------------------
__global__ __launch_bounds__(256) void k_agg(
    const int* __restrict__ rowstart, const int* __restrict__ csr,
    const float* __restrict__ aS, const float* __restrict__ aD,
    const float4* __restrict__ hW4, const float4* __restrict__ bgat4,
    const float* __restrict__ W1, const float* __restrict__ b1,
    const float* __restrict__ W2, const float* __restrict__ b2,
    float2* __restrict__ out)
{
    __shared__ __align__(16) float rowbuf[4][HID];   // per-wave 512 B

    const int t = threadIdx.x;
    const int w = t >> 6;
    const int n = blockIdx.x * 4 + w;
    const int lane = t & 63;
    const int slot = lane >> 3;      // 8 parallel edge slots
    const int cg   = lane & 7;       // colgroup: cols [cg*16, cg*16+16)
    const int head = cg >> 1;

    const int r0 = rowstart[n], r1 = rowstart[n + 1];
    const float adh = aD[n * 4 + head];

    float4 a0 = {0.f,0.f,0.f,0.f}, a1 = {0.f,0.f,0.f,0.f};
    float4 a2 = {0.f,0.f,0.f,0.f}, a3 = {0.f,0.f,0.f,0.f};
    float ss = 0.0f;

#define ACC16(H0, H1, H2, H3, X)                                               \
    a0.x = fmaf(H0.x, X, a0.x); a0.y = fmaf(H0.y, X, a0.y);                    \
    a0.z = fmaf(H0.z, X, a0.z); a0.w = fmaf(H0.w, X, a0.w);                    \
    a1.x = fmaf(H1.x, X, a1.x); a1.y = fmaf(H1.y, X, a1.y);                    \
    a1.z = fmaf(H1.z, X, a1.z); a1.w = fmaf(H1.w, X, a1.w);                    \
    a2.x = fmaf(H2.x, X, a2.x); a2.y = fmaf(H2.y, X, a2.y);                    \
    a2.z = fmaf(H2.z, X, a2.z); a2.w = fmaf(H2.w, X, a2.w);                    \
    a3.x = fmaf(H3.x, X, a3.x); a3.y = fmaf(H3.y, X, a3.y);                    \
    a3.z = fmaf(H3.z, X, a3.z); a3.w = fmaf(H3.w, X, a3.w);

    // self-loop: processed once (by slot-0 lanes), reduced with the rest
    if (slot == 0) {
        const float x0 = __expf(lrelu(aS[n * 4 + head] + adh));
        const float4* p0 = &hW4[(size_t)n * 32 + cg * 4];
        const float4 h00 = p0[0], h01 = p0[1], h02 = p0[2], h03 = p0[3];
        ACC16(h00, h01, h02, h03, x0)
        ss += x0;
    }

    int j = r0 + slot;
    for (; j + 8 < r1; j += 16) {
        const int s0 = csr[j], s1 = csr[j + 8];
        const float x0 = __expf(lrelu(aS[s0 * 4 + head] + adh));
        const float x1 = __expf(lrelu(aS[s1 * 4 + head] + adh));
        const float4* p0 = &hW4[(size_t)s0 * 32 + cg * 4];
        const float4* p1 = &hW4[(size_t)s1 * 32 + cg * 4];
        const float4 h00 = p0[0], h01 = p0[1], h02 = p0[2], h03 = p0[3];
        const float4 h10 = p1[0], h11 = p1[1], h12 = p1[2], h13 = p1[3];
        ACC16(h00, h01, h02, h03, x0)
        ACC16(h10, h11, h12, h13, x1)
        ss += x0 + x1;
    }
    if (j < r1) {
        const int s0 = csr[j];
        const float x0 = __expf(lrelu(aS[s0 * 4 + head] + adh));
        const float4* p0 = &hW4[(size_t)s0 * 32 + cg * 4];
        const float4 h00 = p0[0], h01 = p0[1], h02 = p0[2], h03 = p0[3];
        ACC16(h00, h01, h02, h03, x0)
        ss += x0;
    }
#undef ACC16

    // reduce across the 8 edge-slots (lane bits 3..5)
#pragma unroll
    for (int off = 8; off <= 32; off <<= 1) {
        a0.x += __shfl_xor(a0.x, off); a0.y += __shfl_xor(a0.y, off);
        a0.z += __shfl_xor(a0.z, off); a0.w += __shfl_xor(a0.w, off);
        a1.x += __shfl_xor(a1.x, off); a1.y += __shfl_xor(a1.y, off);
        a1.z += __shfl_xor(a1.z, off); a1.w += __shfl_xor(a1.w, off);
        a2.x += __shfl_xor(a2.x, off); a2.y += __shfl_xor(a2.y, off);
        a2.z += __shfl_xor(a2.z, off); a2.w += __shfl_xor(a2.w, off);
        a3.x += __shfl_xor(a3.x, off); a3.y += __shfl_xor(a3.y, off);
        a3.z += __shfl_xor(a3.z, off); a3.w += __shfl_xor(a3.w, off);
        ss += __shfl_xor(ss, off);
    }

    // slot-0 lanes own 16 cols each: normalize, +b_gat, park in LDS rowbuf
    if (slot == 0) {
        const float inv = 1.0f / (ss + 1e-16f);
        const float4 bg0 = bgat4[cg * 4 + 0];
        const float4 bg1 = bgat4[cg * 4 + 1];
        const float4 bg2 = bgat4[cg * 4 + 2];
        const float4 bg3 = bgat4[cg * 4 + 3];
        float4 o0, o1, o2, o3;
        o0.x = a0.x * inv + bg0.x; o0.y = a0.y * inv + bg0.y;
        o0.z = a0.z * inv + bg0.z; o0.w = a0.w * inv + bg0.w;
        o1.x = a1.x * inv + bg1.x; o1.y = a1.y * inv + bg1.y;
        o1.z = a1.z * inv + bg1.z; o1.w = a1.w * inv + bg1.w;
        o2.x = a2.x * inv + bg2.x; o2.y = a2.y * inv + bg2.y;
        o2.z = a2.z * inv + bg2.z; o2.w = a2.w * inv + bg2.w;
        o3.x = a3.x * inv + bg3.x; o3.y = a3.y * inv + bg3.y;
        o3.z = a3.z * inv + bg3.z; o3.w = a3.w * inv + bg3.w;
        float* pr = &rowbuf[w][cg * 16];
        *(float4*)&pr[0]  = o0;
        *(float4*)&pr[4]  = o1;
        *(float4*)&pr[8]  = o2;
        *(float4*)&pr[12] = o3;
    }
    // same-wave LDS write->read: in-order per wave, no barrier needed

    // ---- fused MLP head: h2[lane] = relu(row@W1+b1); logits = h2@W2+b2 ----
    float acc = b1[lane];
#pragma unroll 8
    for (int k = 0; k < HID; k += 4) {
        const float4 rv = *(const float4*)&rowbuf[w][k];
        acc = fmaf(rv.x, W1[(k + 0) * 64 + lane], acc);
        acc = fmaf(rv.y, W1[(k + 1) * 64 + lane], acc);
        acc = fmaf(rv.z, W1[(k + 2) * 64 + lane], acc);
        acc = fmaf(rv.w, W1[(k + 3) * 64 + lane], acc);
    }
    acc = fmaxf(acc, 0.0f);

    float l0 = acc * W2[lane * 2 + 0];
    float l1 = acc * W2[lane * 2 + 1];
#pragma unroll
    for (int off = 32; off >= 1; off >>= 1) {
        l0 += __shfl_xor(l0, off);
        l1 += __shfl_xor(l1, off);
    }
    if (lane == 0) out[n] = make_float2(l0 + b2[0], l1 + b2[1]);
}

extern "C" void kernel_launch(void* const* d_in, const int* in_sizes, int n_in,
                              void* d_out, int out_size, void* d_ws, size_t ws_size,
                              hipStream_t stream) {
    const float* x     = (const float*)d_in[0];
    const int*   ei    = (const int*)d_in[1];
    const float* Win   = (const float*)d_in[2];
    const float* bin   = (const float*)d_in[3];
    const float* Wgat  = (const float*)d_in[4];
    const float* attS  = (const float*)d_in[5];
    const float* attD  = (const float*)d_in[6];
    const float* bgat  = (const float*)d_in[7];
    const float* W1    = (const float*)d_in[8];
    const float* b1    = (const float*)d_in[9];
    const float* W2    = (const float*)d_in[10];
    const float* b2    = (const float*)d_in[11];

    char* ws = (char*)d_ws;
    float* hW    = (float*)(ws + HW_OFF);
    float* aS    = (float*)(ws + ASRC_OFF);
    float* aD    = (float*)(ws + ADST_OFF);
    int*   deg   = (int*)(ws + DEG_OFF);
    int*   row   = (int*)(ws + ROW_OFF);
    int*   cur   = (int*)(ws + CUR_OFF);
    int*   bsum  = (int*)(ws + BSUM_OFF);
    int*   csr   = (int*)(ws + CSR_OFF);

    hipMemsetAsync(ws + DEG_OFF, 0, N * sizeof(int), stream);

    k_proj<<<PROJ_NB, 256, 0, stream>>>(x, Win, bin, Wgat, attS, attD,
                                        hW, aS, aD, ei, deg);
    k_scan1<<<SCAN_NB, 256, 0, stream>>>(deg, bsum);
    k_scan23<<<SCAN_NB, 256, 0, stream>>>(deg, bsum, row, cur);
    k_scatter<<<(E + 255) / 256, 256, 0, stream>>>(ei, cur, csr);
    k_agg<<<N / 4, 256, 0, stream>>>(row, csr, aS, aD, (const float4*)hW,
                                     (const float4*)bgat, W1, b1, W2, b2,
                                     (float2*)d_out);
}